// Round 3
// baseline (628.121 us; speedup 1.0000x reference)
//
#include <hip/hip_runtime.h>
#include <hip/hip_bf16.h>

// GeneratorSDF: latent-conditioned MLP SDF on a 128^3 grid.
// dims: 67 -> 128 -> 64 -> 32 -> 1 (relu, relu, relu, sigmoid)
// Latent x (64 dims) is constant across all 2M points => fold into base1[128].
//
// DTYPE-ADAPTIVE (round-2 post-mortem): rounds 1-2 produced exactly-zero
// output, consistent with fp32 buffers read as bf16 (garbage exponents ->
// point-independent saturated sigmoid -> all 0s). We detect fp32 vs bf16 on
// device: W2's first 128 elements read AS BF16 are all |v| <= 1/sqrt(128) if
// truly bf16; if truly fp32, odd elements are random-exponent mantissa halves
// (P(all <= 0.25) ~ 1e-20). The flag is block-uniform; wrong-dtype loads and
// stores (potentially OOB) sit in untaken uniform branches and never issue.

#define GRIDN 128
#define NPTS (GRIDN * GRIDN * GRIDN)

__device__ __forceinline__ bool detect_fp32(const void* W2) {
    // Reads 256 bytes; in-bounds under either interpretation (W2 >= 16 KB).
    const __hip_bfloat16* p = (const __hip_bfloat16*)W2;
    bool bad = false;
    for (int i = 0; i < 128; ++i) {
        float v = __bfloat162float(p[i]);
        bad = bad || !(fabsf(v) <= 0.25f);  // catches huge AND NaN
    }
    return bad;  // true => buffers are fp32
}

template <typename T>
__device__ __forceinline__ void fill_weights(
    const T* __restrict__ x, const T* __restrict__ W1, const T* __restrict__ b1,
    const T* __restrict__ W2, const T* __restrict__ b2,
    const T* __restrict__ W3, const T* __restrict__ b3,
    const T* __restrict__ W4, const T* __restrict__ b4,
    float* s_x, float4* s_c1, float* s_w2, float* s_b2,
    float* s_w3, float* s_b3, float* s_w4, float* s_b4, int t) {
    if (t < 64) s_x[t] = (float)x[t];
    __syncthreads();  // uniform: all threads are in the same instantiation

    // W2 [64 x 128] row-major (idx = o*128 + k) -> column-major LDS [k*64 + o]
#pragma unroll
    for (int i = 0; i < 32; ++i) {
        int idx = t + 256 * i;
        int o = idx >> 7, k = idx & 127;
        s_w2[k * 64 + o] = (float)W2[idx];
    }
    // W3 [32 x 64] row-major (idx = o*64 + k) -> column-major LDS [k*32 + o]
#pragma unroll
    for (int i = 0; i < 8; ++i) {
        int idx = t + 256 * i;
        int o = idx >> 6, k = idx & 63;
        s_w3[k * 32 + o] = (float)W3[idx];
    }
    if (t < 64) s_b2[t] = (float)b2[t];
    if (t < 32) {
        s_b3[t] = (float)b3[t];
        s_w4[t] = (float)W4[t];
    }
    if (t == 0) s_b4[0] = (float)b4[0];
    // base1[o] = b1[o] + sum_{c<64} W1[o][c]*x[c]; coord weights W1[o][64..66]
    if (t < 128) {
        float s = (float)b1[t];
        const T* w1row = W1 + t * 67;
#pragma unroll 8
        for (int c = 0; c < 64; ++c) s += (float)w1row[c] * s_x[c];
        float4 v;
        v.x = s;
        v.y = (float)w1row[64];
        v.z = (float)w1row[65];
        v.w = (float)w1row[66];
        s_c1[t] = v;
    }
}

// 256 threads/block, 2 points/thread => 512 points/block, 4096 blocks.
__global__ __launch_bounds__(256, 2) void mlp_kernel(
    const void* __restrict__ x,  const void* __restrict__ W1,
    const void* __restrict__ b1, const void* __restrict__ W2,
    const void* __restrict__ b2, const void* __restrict__ W3,
    const void* __restrict__ b3, const void* __restrict__ W4,
    const void* __restrict__ b4, void* __restrict__ out) {
    __shared__ float s_x[64];
    __shared__ float4 s_c1[128];   // {base1, wa, wb, wc} per layer-1 output
    __shared__ float s_w2[8192];   // 32 KB, col-major [k*64+o]
    __shared__ float s_b2[64];
    __shared__ float s_w3[2048];   // 8 KB, col-major [k*32+o]
    __shared__ float s_b3[32];
    __shared__ float s_w4[32];
    __shared__ float s_b4[1];

    const int t = threadIdx.x;
    const bool is_f32 = detect_fp32(W2);  // block-uniform

    if (is_f32) {
        fill_weights<float>((const float*)x, (const float*)W1, (const float*)b1,
                            (const float*)W2, (const float*)b2, (const float*)W3,
                            (const float*)b3, (const float*)W4, (const float*)b4,
                            s_x, s_c1, s_w2, s_b2, s_w3, s_b3, s_w4, s_b4, t);
    } else {
        fill_weights<__hip_bfloat16>(
            (const __hip_bfloat16*)x, (const __hip_bfloat16*)W1,
            (const __hip_bfloat16*)b1, (const __hip_bfloat16*)W2,
            (const __hip_bfloat16*)b2, (const __hip_bfloat16*)W3,
            (const __hip_bfloat16*)b3, (const __hip_bfloat16*)W4,
            (const __hip_bfloat16*)b4,
            s_x, s_c1, s_w2, s_b2, s_w3, s_b3, s_w4, s_b4, t);
    }
    __syncthreads();

    // ---- 2 points per thread ----
    const int n0 = blockIdx.x * 512 + t;
    const int n1 = n0 + 256;
    const float step = 2.0f / 127.0f;

    const int i0 = n0 >> 14, j0 = (n0 >> 7) & 127, kk0 = n0 & 127;
    const int i1 = n1 >> 14, j1 = (n1 >> 7) & 127, kk1 = n1 & 127;
    const float pa0 = -1.0f + step * (float)i0;
    const float pb0 = -1.0f + step * (float)j0;
    const float pc0 = -1.0f + step * (float)kk0;
    const float pa1 = -1.0f + step * (float)i1;
    const float pb1 = -1.0f + step * (float)j1;
    const float pc1 = -1.0f + step * (float)kk1;

    float acc0[64], acc1[64];
#pragma unroll
    for (int j = 0; j < 64; ++j) {
        acc0[j] = 0.0f;
        acc1[j] = 0.0f;
    }

    // ---- layer 2 (layer-1 activation computed on the fly): k over 128 ----
    for (int k = 0; k < 128; ++k) {
        float4 c = s_c1[k];  // wave-uniform broadcast, conflict-free
        float h0 = fmaxf(c.x + c.y * pa0 + c.z * pb0 + c.w * pc0, 0.0f);
        float h1 = fmaxf(c.x + c.y * pa1 + c.z * pb1 + c.w * pc1, 0.0f);
        const float4* col = (const float4*)&s_w2[k * 64];
#pragma unroll
        for (int jj = 0; jj < 16; ++jj) {
            float4 w = col[jj];
            acc0[4 * jj + 0] += w.x * h0;
            acc1[4 * jj + 0] += w.x * h1;
            acc0[4 * jj + 1] += w.y * h0;
            acc1[4 * jj + 1] += w.y * h1;
            acc0[4 * jj + 2] += w.z * h0;
            acc1[4 * jj + 2] += w.z * h1;
            acc0[4 * jj + 3] += w.w * h0;
            acc1[4 * jj + 3] += w.w * h1;
        }
    }

    // ---- layer 3: k over 64 ----
    float a30[32], a31[32];
#pragma unroll
    for (int o = 0; o < 32; ++o) {
        a30[o] = 0.0f;
        a31[o] = 0.0f;
    }
#pragma unroll
    for (int k = 0; k < 64; ++k) {
        float h0 = fmaxf(acc0[k] + s_b2[k], 0.0f);
        float h1 = fmaxf(acc1[k] + s_b2[k], 0.0f);
        const float4* col = (const float4*)&s_w3[k * 32];
#pragma unroll
        for (int jj = 0; jj < 8; ++jj) {
            float4 w = col[jj];
            a30[4 * jj + 0] += w.x * h0;
            a31[4 * jj + 0] += w.x * h1;
            a30[4 * jj + 1] += w.y * h0;
            a31[4 * jj + 1] += w.y * h1;
            a30[4 * jj + 2] += w.z * h0;
            a31[4 * jj + 2] += w.z * h1;
            a30[4 * jj + 3] += w.w * h0;
            a31[4 * jj + 3] += w.w * h1;
        }
    }

    // ---- layer 4 + sigmoid ----
    float z0 = s_b4[0], z1 = s_b4[0];
#pragma unroll
    for (int o = 0; o < 32; ++o) {
        float h0 = fmaxf(a30[o] + s_b3[o], 0.0f);
        float h1 = fmaxf(a31[o] + s_b3[o], 0.0f);
        float w = s_w4[o];
        z0 += w * h0;
        z1 += w * h1;
    }
    float sig0 = 1.0f / (1.0f + __expf(-z0));
    float sig1 = 1.0f / (1.0f + __expf(-z1));

    if (is_f32) {
        float* outf = (float*)out;
        outf[n0] = sig0;
        outf[n1] = sig1;
    } else {
        __hip_bfloat16* outb = (__hip_bfloat16*)out;
        outb[n0] = __float2bfloat16(sig0);
        outb[n1] = __float2bfloat16(sig1);
    }
}

extern "C" void kernel_launch(void* const* d_in, const int* in_sizes, int n_in,
                              void* d_out, int out_size, void* d_ws, size_t ws_size,
                              hipStream_t stream) {
    mlp_kernel<<<NPTS / 512, 256, 0, stream>>>(d_in[0], d_in[1], d_in[2], d_in[3],
                                               d_in[4], d_in[5], d_in[6], d_in[7],
                                               d_in[8], d_out);
}

// Round 4
// 187.393 us; speedup vs baseline: 3.3519x; 3.3519x over previous
//
#include <hip/hip_runtime.h>
#include <hip/hip_bf16.h>

// GeneratorSDF: latent-conditioned MLP SDF on a 128^3 grid (fp32 I/O, confirmed R3).
// dims: 67 -> 128 -> 64 -> 32 -> 1 (relu, relu, relu, sigmoid)
// Latent x (64) is constant across points => folded into c1 = {base1, wa, wb, wc}.
//
// R4: MFMA rewrite. Layers 2/3 via v_mfma_f32_16x16x32_bf16 (fp32 accumulate).
//  - Verified layouts (guide m89/m91): A[m=lane&15][k=(lane>>4)*8+j],
//    B[k=(lane>>4)*8+j][n=lane&15], C/D row=(lane>>4)*4+reg, col=lane&15.
//  - h1 computed per-lane straight into B-fragment registers (no LDS trip).
//  - Layer-2 C-layout -> layer-3 B-layout via small per-wave LDS relayout.
//  - Biases folded into MFMA C-init.

#define NPTS (128 * 128 * 128)

typedef float f32x4_t __attribute__((ext_vector_type(4)));
typedef short bf16x8_t __attribute__((ext_vector_type(8)));

__device__ __forceinline__ unsigned short f2bf(float f) {
    unsigned u = __builtin_bit_cast(unsigned, f);
    return (unsigned short)((u + 0x7fffu + ((u >> 16) & 1u)) >> 16);  // RNE
}

__global__ __launch_bounds__(256, 2) void mlp_kernel(
    const float* __restrict__ x,  const float* __restrict__ W1,
    const float* __restrict__ b1, const float* __restrict__ W2,
    const float* __restrict__ b2, const float* __restrict__ W3,
    const float* __restrict__ b3, const float* __restrict__ W4,
    const float* __restrict__ b4, float* __restrict__ out) {
    __shared__ float4 s_c1[128];                          // {base1, wa, wb, wc}
    __shared__ __align__(16) unsigned short s_w2a[16][64][8];  // A-frags L2: frag=mt*4+kb
    __shared__ __align__(16) unsigned short s_w3a[4][64][8];   // A-frags L3: frag=mt*2+kb
    __shared__ float s_b2[64];
    __shared__ float s_b3[32];
    __shared__ float s_w4[32];
    __shared__ __align__(16) unsigned short s_h2[4][16][72];   // per-wave [n][k], +8 pad

    const int t = threadIdx.x;
    const int w = t >> 6;
    const int lane = t & 63;
    const int quad = lane >> 4;
    const int l15 = lane & 15;

    // ================= prep (per block) =================
    // c1: fold latent. base1[o] = b1[o] + sum_c W1[o][c]*x[c]
    if (t < 128) {
        float s = b1[t];
        const float* w1row = W1 + t * 67;
#pragma unroll 8
        for (int c = 0; c < 64; ++c) s = fmaf(w1row[c], x[c], s);
        float4 v;
        v.x = s;
        v.y = w1row[64];
        v.z = w1row[65];
        v.w = w1row[66];
        s_c1[t] = v;
    }
    // W2 [64][128] -> bf16 A-fragment layout
#pragma unroll
    for (int it = 0; it < 32; ++it) {
        int idx = t + 256 * it;
        int o = idx >> 7, k = idx & 127;
        int mt = o >> 4, lm = o & 15;
        int kb = k >> 5, q = (k >> 3) & 3, jj = k & 7;
        s_w2a[mt * 4 + kb][q * 16 + lm][jj] = f2bf(W2[idx]);
    }
    // W3 [32][64] -> bf16 A-fragment layout
#pragma unroll
    for (int it = 0; it < 8; ++it) {
        int idx = t + 256 * it;
        int o = idx >> 6, k = idx & 63;
        int mt = o >> 4, lm = o & 15;
        int kb = k >> 5, q = (k >> 3) & 3, jj = k & 7;
        s_w3a[mt * 2 + kb][q * 16 + lm][jj] = f2bf(W3[idx]);
    }
    if (t < 64) s_b2[t] = b2[t];
    if (t < 32) {
        s_b3[t] = b3[t];
        s_w4[t] = W4[t];
    }
    const float bias4 = b4[0];
    __syncthreads();

    // ================= per-wave fragment preload =================
    bf16x8_t a2[16];
#pragma unroll
    for (int f = 0; f < 16; ++f) a2[f] = *(const bf16x8_t*)&s_w2a[f][lane][0];
    bf16x8_t a3[4];
#pragma unroll
    for (int f = 0; f < 4; ++f) a3[f] = *(const bf16x8_t*)&s_w3a[f][lane][0];
    float4 b2q[4];
#pragma unroll
    for (int mt = 0; mt < 4; ++mt) b2q[mt] = *(const float4*)&s_b2[mt * 16 + quad * 4];
    float4 b3q[2], w4q[2];
#pragma unroll
    for (int mt = 0; mt < 2; ++mt) {
        b3q[mt] = *(const float4*)&s_b3[mt * 16 + quad * 4];
        w4q[mt] = *(const float4*)&s_w4[mt * 16 + quad * 4];
    }

    const float step = 2.0f / 127.0f;

    // ================= 4 n-groups of 16 points per wave =================
#pragma unroll 1
    for (int ng = 0; ng < 4; ++ng) {
        const int n = blockIdx.x * 256 + w * 64 + ng * 16 + l15;
        const int gi = n >> 14, gj = (n >> 7) & 127, gk = n & 127;
        const float pa = -1.0f + step * (float)gi;
        const float pb = -1.0f + step * (float)gj;
        const float pc = -1.0f + step * (float)gk;

        // ---- h1 directly into B-fragments: B[k=quad*8+jj][n=l15] ----
        bf16x8_t bfrag[4];
#pragma unroll
        for (int kb = 0; kb < 4; ++kb) {
            unsigned short tmp[8];
#pragma unroll
            for (int jj = 0; jj < 8; ++jj) {
                float4 c = s_c1[kb * 32 + quad * 8 + jj];
                float h = fmaf(c.w, pc, fmaf(c.z, pb, fmaf(c.y, pa, c.x)));
                tmp[jj] = f2bf(fmaxf(h, 0.0f));
            }
            bf16x8_t v;
#pragma unroll
            for (int jj = 0; jj < 8; ++jj) v[jj] = (short)tmp[jj];
            bfrag[kb] = v;
        }

        // ---- layer 2: 4 M-tiles x 4 K-blocks, bias in C-init ----
        f32x4_t acc2[4];
#pragma unroll
        for (int mt = 0; mt < 4; ++mt) {
            f32x4_t c;
            c[0] = b2q[mt].x; c[1] = b2q[mt].y; c[2] = b2q[mt].z; c[3] = b2q[mt].w;
#pragma unroll
            for (int kb = 0; kb < 4; ++kb)
                c = __builtin_amdgcn_mfma_f32_16x16x32_bf16(a2[mt * 4 + kb], bfrag[kb], c, 0, 0, 0);
            acc2[mt] = c;
        }

        // ---- relu + relayout C->B via per-wave LDS scratch ----
        __syncthreads();  // protect scratch from previous iteration's readers
#pragma unroll
        for (int mt = 0; mt < 4; ++mt) {
            unsigned short p0 = f2bf(fmaxf(acc2[mt][0], 0.0f));
            unsigned short p1 = f2bf(fmaxf(acc2[mt][1], 0.0f));
            unsigned short p2 = f2bf(fmaxf(acc2[mt][2], 0.0f));
            unsigned short p3 = f2bf(fmaxf(acc2[mt][3], 0.0f));
            uint2 pk;
            pk.x = (unsigned)p0 | ((unsigned)p1 << 16);
            pk.y = (unsigned)p2 | ((unsigned)p3 << 16);
            *(uint2*)&s_h2[w][l15][mt * 16 + quad * 4] = pk;
        }
        __syncthreads();

        // ---- layer 3: 2 M-tiles x 2 K-blocks ----
        bf16x8_t b3f[2];
#pragma unroll
        for (int kb = 0; kb < 2; ++kb) b3f[kb] = *(const bf16x8_t*)&s_h2[w][l15][kb * 32 + quad * 8];
        f32x4_t acc3[2];
#pragma unroll
        for (int mt = 0; mt < 2; ++mt) {
            f32x4_t c;
            c[0] = b3q[mt].x; c[1] = b3q[mt].y; c[2] = b3q[mt].z; c[3] = b3q[mt].w;
#pragma unroll
            for (int kb = 0; kb < 2; ++kb)
                c = __builtin_amdgcn_mfma_f32_16x16x32_bf16(a3[mt * 2 + kb], b3f[kb], c, 0, 0, 0);
            acc3[mt] = c;
        }

        // ---- layer 4: dot over lane's 8 rows + cross-quad reduce + sigmoid ----
        float z = 0.0f;
#pragma unroll
        for (int mt = 0; mt < 2; ++mt) {
            z = fmaf(w4q[mt].x, fmaxf(acc3[mt][0], 0.0f), z);
            z = fmaf(w4q[mt].y, fmaxf(acc3[mt][1], 0.0f), z);
            z = fmaf(w4q[mt].z, fmaxf(acc3[mt][2], 0.0f), z);
            z = fmaf(w4q[mt].w, fmaxf(acc3[mt][3], 0.0f), z);
        }
        z += __shfl_xor(z, 16);
        z += __shfl_xor(z, 32);
        z += bias4;
        float sig = 1.0f / (1.0f + __expf(-z));
        if (quad == 0) out[n] = sig;
    }
}

extern "C" void kernel_launch(void* const* d_in, const int* in_sizes, int n_in,
                              void* d_out, int out_size, void* d_ws, size_t ws_size,
                              hipStream_t stream) {
    mlp_kernel<<<NPTS / 256, 256, 0, stream>>>(
        (const float*)d_in[0], (const float*)d_in[1], (const float*)d_in[2],
        (const float*)d_in[3], (const float*)d_in[4], (const float*)d_in[5],
        (const float*)d_in[6], (const float*)d_in[7], (const float*)d_in[8],
        (float*)d_out);
}

// Round 6
// 178.012 us; speedup vs baseline: 3.5285x; 1.0527x over previous
//
#include <hip/hip_runtime.h>
#include <hip/hip_bf16.h>

// GeneratorSDF: latent-conditioned MLP SDF on a 128^3 grid (fp32 I/O).
// dims: 67 -> 128 -> 64 -> 32 -> 1 (relu, relu, relu, sigmoid)
//
// R6 = R5 with the __builtin_bit_cast -> __builtin_memcpy fix (ROCm's
// __hip_bfloat162 is not trivially copyable).
// R5 theory (from R4 post-mortem, 139us @ MfmaUtil 13 / VALUBusy 70):
//  - Per-block coordinate folding: within a 256-pt block pa is constant and pb
//    takes 2 values (wave-uniform select) => h1 = d.x + wc*pc: 1 fma (was 3).
//  - Packed bf16 converts (__float22bfloat162_rn) everywhere (was 3-op RNE).
//  - No in-loop __syncthreads(): h2 scratch is per-wave; DS ops are in-order
//    within a wave and the compiler inserts lgkmcnt waits on the RAW.
//  - XOR-swizzle (l15&1)*32 on h2 scratch to break 8-way read conflicts.
// MFMA layouts (verified m89/m91): A[m=lane&15][k=quad*8+j],
// B[k=quad*8+j][n=lane&15], C/D row=quad*4+reg, col=lane&15.

#define NPTS (128 * 128 * 128)

typedef float f32x4_t __attribute__((ext_vector_type(4)));
typedef short bf16x8_t __attribute__((ext_vector_type(8)));

__device__ __forceinline__ unsigned pk2(float lo, float hi) {
    __hip_bfloat162 p = __float22bfloat162_rn(make_float2(lo, hi));
    unsigned u;
    __builtin_memcpy(&u, &p, sizeof(u));
    return u;
}

__global__ __launch_bounds__(256, 2) void mlp_kernel(
    const float* __restrict__ x,  const float* __restrict__ W1,
    const float* __restrict__ b1, const float* __restrict__ W2,
    const float* __restrict__ b2, const float* __restrict__ W3,
    const float* __restrict__ b3, const float* __restrict__ W4,
    const float* __restrict__ b4, float* __restrict__ out) {
    __shared__ float2 s_d[2][128];                             // {base+wa*pa+wb*pb_j, wc}
    __shared__ __align__(16) unsigned short s_w2a[16][64][8];  // L2 A-frags: f = mt*4+kb
    __shared__ __align__(16) unsigned short s_w3a[4][64][8];   // L3 A-frags: f = mt*2+kb
    __shared__ float s_b2[64];
    __shared__ float s_b3[32];
    __shared__ float s_w4[32];
    __shared__ __align__(16) unsigned short s_h2[4][16][72];   // per-wave [n][c], swizzled

    const int t = threadIdx.x;
    const int w = t >> 6;
    const int lane = t & 63;
    const int quad = lane >> 4;
    const int l15 = lane & 15;
    const float step = 2.0f / 127.0f;

    // ================= per-block prep =================
    // base1[o] = b1[o] + sum_c W1[o][c]*x[c]; fold pa (block-const) and both pb.
    if (t < 128) {
        const float* w1row = W1 + t * 67;
        float s = b1[t];
#pragma unroll 8
        for (int c = 0; c < 64; ++c) s = fmaf(w1row[c], x[c], s);
        const float wa = w1row[64], wb = w1row[65], wc = w1row[66];
        const float pa = -1.0f + step * (float)(blockIdx.x >> 6);
        const int gj0 = (blockIdx.x * 2) & 127;  // even, gj0+1 <= 127
        const float pb0 = -1.0f + step * (float)gj0;
        const float base = fmaf(wa, pa, s);
        s_d[0][t] = make_float2(fmaf(wb, pb0, base), wc);
        s_d[1][t] = make_float2(fmaf(wb, pb0 + step, base), wc);
    }
    // W2 [64][128] -> bf16 A-frag layout, pair-packed (coalesced float2 loads)
    const float2* W2v = (const float2*)W2;
#pragma unroll
    for (int it = 0; it < 16; ++it) {
        int pidx = t + 256 * it;
        int idx2 = pidx * 2;
        int o = idx2 >> 7, k = idx2 & 127;  // k even
        int mt = o >> 4, lm = o & 15;
        int kb = k >> 5, q = (k >> 3) & 3, jj = k & 7;
        float2 v = W2v[pidx];
        *(unsigned*)&s_w2a[mt * 4 + kb][q * 16 + lm][jj] = pk2(v.x, v.y);
    }
    // W3 [32][64] -> bf16 A-frag layout
    const float2* W3v = (const float2*)W3;
#pragma unroll
    for (int it = 0; it < 4; ++it) {
        int pidx = t + 256 * it;
        int idx2 = pidx * 2;
        int o = idx2 >> 6, k = idx2 & 63;
        int mt = o >> 4, lm = o & 15;
        int kb = k >> 5, q = (k >> 3) & 3, jj = k & 7;
        float2 v = W3v[pidx];
        *(unsigned*)&s_w3a[mt * 2 + kb][q * 16 + lm][jj] = pk2(v.x, v.y);
    }
    if (t < 64) s_b2[t] = b2[t];
    if (t < 32) {
        s_b3[t] = b3[t];
        s_w4[t] = W4[t];
    }
    const float bias4 = b4[0];
    __syncthreads();  // the only barrier

    // ================= per-wave fragment preload =================
    bf16x8_t a2[16];
#pragma unroll
    for (int f = 0; f < 16; ++f) a2[f] = *(const bf16x8_t*)&s_w2a[f][lane][0];
    bf16x8_t a3[4];
#pragma unroll
    for (int f = 0; f < 4; ++f) a3[f] = *(const bf16x8_t*)&s_w3a[f][lane][0];
    float4 b2q[4];
#pragma unroll
    for (int mt = 0; mt < 4; ++mt) b2q[mt] = *(const float4*)&s_b2[mt * 16 + quad * 4];
    float4 b3q[2], w4q[2];
#pragma unroll
    for (int mt = 0; mt < 2; ++mt) {
        b3q[mt] = *(const float4*)&s_b3[mt * 16 + quad * 4];
        w4q[mt] = *(const float4*)&s_w4[mt * 16 + quad * 4];
    }
    // pb selector: bit7 of (w*64 + ng*16 + l15) == (w >= 2) for all ng,l15
    const float2* dj = &s_d[w >> 1][0];
    const int sw = (l15 & 1) * 32;  // h2 c-swizzle (shorts)

    // ================= 4 n-groups of 16 points per wave =================
#pragma unroll 1
    for (int ng = 0; ng < 4; ++ng) {
        const int off = w * 64 + ng * 16 + l15;
        const int n = blockIdx.x * 256 + off;
        const float pc = -1.0f + step * (float)(off & 127);

        // ---- h1 straight into B-fragments: B[k=kb*32+quad*8+jj][n=l15] ----
        bf16x8_t bfrag[4];
#pragma unroll
        for (int kb = 0; kb < 4; ++kb) {
            union { bf16x8_t v; unsigned u[4]; } bb;
#pragma unroll
            for (int jp = 0; jp < 4; ++jp) {
                float2 d0 = dj[kb * 32 + quad * 8 + 2 * jp];
                float2 d1 = dj[kb * 32 + quad * 8 + 2 * jp + 1];
                float h0 = fmaxf(fmaf(d0.y, pc, d0.x), 0.0f);
                float h1 = fmaxf(fmaf(d1.y, pc, d1.x), 0.0f);
                bb.u[jp] = pk2(h0, h1);
            }
            bfrag[kb] = bb.v;
        }

        // ---- layer 2: 4 M-tiles x 4 K-blocks, bias in C-init ----
        f32x4_t acc2[4];
#pragma unroll
        for (int mt = 0; mt < 4; ++mt) {
            f32x4_t c;
            c[0] = b2q[mt].x; c[1] = b2q[mt].y; c[2] = b2q[mt].z; c[3] = b2q[mt].w;
#pragma unroll
            for (int kb = 0; kb < 4; ++kb)
                c = __builtin_amdgcn_mfma_f32_16x16x32_bf16(a2[mt * 4 + kb], bfrag[kb], c, 0, 0, 0);
            acc2[mt] = c;
        }

        // ---- relu + C->B relayout via per-wave LDS (no barrier needed) ----
#pragma unroll
        for (int mt = 0; mt < 4; ++mt) {
            uint2 pk;
            pk.x = pk2(fmaxf(acc2[mt][0], 0.0f), fmaxf(acc2[mt][1], 0.0f));
            pk.y = pk2(fmaxf(acc2[mt][2], 0.0f), fmaxf(acc2[mt][3], 0.0f));
            *(uint2*)&s_h2[w][l15][(mt * 16 + quad * 4) ^ sw] = pk;
        }

        // ---- layer 3: 2 M-tiles x 2 K-blocks ----
        bf16x8_t b3f[2];
#pragma unroll
        for (int kb = 0; kb < 2; ++kb)
            b3f[kb] = *(const bf16x8_t*)&s_h2[w][l15][((kb * 32) ^ sw) + quad * 8];
        f32x4_t acc3[2];
#pragma unroll
        for (int mt = 0; mt < 2; ++mt) {
            f32x4_t c;
            c[0] = b3q[mt].x; c[1] = b3q[mt].y; c[2] = b3q[mt].z; c[3] = b3q[mt].w;
#pragma unroll
            for (int kb = 0; kb < 2; ++kb)
                c = __builtin_amdgcn_mfma_f32_16x16x32_bf16(a3[mt * 2 + kb], b3f[kb], c, 0, 0, 0);
            acc3[mt] = c;
        }

        // ---- layer 4 + sigmoid ----
        float z = 0.0f;
#pragma unroll
        for (int mt = 0; mt < 2; ++mt) {
            z = fmaf(w4q[mt].x, fmaxf(acc3[mt][0], 0.0f), z);
            z = fmaf(w4q[mt].y, fmaxf(acc3[mt][1], 0.0f), z);
            z = fmaf(w4q[mt].z, fmaxf(acc3[mt][2], 0.0f), z);
            z = fmaf(w4q[mt].w, fmaxf(acc3[mt][3], 0.0f), z);
        }
        z += __shfl_xor(z, 16);
        z += __shfl_xor(z, 32);
        z += bias4;
        float sig = 1.0f / (1.0f + __expf(-z));
        if (quad == 0) out[n] = sig;
    }
}

extern "C" void kernel_launch(void* const* d_in, const int* in_sizes, int n_in,
                              void* d_out, int out_size, void* d_ws, size_t ws_size,
                              hipStream_t stream) {
    mlp_kernel<<<NPTS / 256, 256, 0, stream>>>(
        (const float*)d_in[0], (const float*)d_in[1], (const float*)d_in[2],
        (const float*)d_in[3], (const float*)d_in[4], (const float*)d_in[5],
        (const float*)d_in[6], (const float*)d_in[7], (const float*)d_in[8],
        (float*)d_out);
}